// Round 1
// baseline (22183.746 us; speedup 1.0000x reference)
//
#include <hip/hip_runtime.h>

constexpr int B = 4, S = 16, D = 1024, DN = 2048, NB = 4, K = 8, VOCAB = 151936;

__device__ __forceinline__ float sigf(float x) { return 1.0f / (1.0f + expf(-x)); }
__device__ __forceinline__ float softplusf(float x) {
  return fmaxf(x, 0.0f) + log1pf(expf(-fabsf(x)));
}

template<int N>
__device__ __forceinline__ void wred(float* a) {
#pragma unroll
  for (int m = 1; m < 64; m <<= 1) {
#pragma unroll
    for (int q = 0; q < N; ++q) a[q] += __shfl_xor(a[q], m, 64);
  }
}

// ---------------- encoder: h = sigmoid(embed[ids] @ enc_W.T + enc_b) ----------------
__global__ __launch_bounds__(256) void enc_kernel(
    const int* __restrict__ token_ids, int t,
    const float* __restrict__ embed, const float* __restrict__ enc_W,
    const float* __restrict__ enc_b, float* __restrict__ h_out) {
  __shared__ float sE[B * D];  // 16KB
  for (int idx = threadIdx.x; idx < (B * D) / 4; idx += 256) {
    int b = idx / (D / 4);
    int c = idx % (D / 4);
    int id = token_ids[b * S + t];
    ((float4*)sE)[idx] = ((const float4*)(embed + (size_t)id * D))[c];
  }
  __syncthreads();
  const int lane = threadIdx.x & 63;
  const int d = (blockIdx.x << 2) + (threadIdx.x >> 6);
  float a[4] = {0.f, 0.f, 0.f, 0.f};
  const float4* wrow = (const float4*)(enc_W + (size_t)d * D);
  for (int c = lane; c < D / 4; c += 64) {
    float4 w = wrow[c];
#pragma unroll
    for (int b = 0; b < 4; ++b) {
      float4 sv = ((const float4*)(sE + b * D))[c];
      a[b] = fmaf(w.x, sv.x, fmaf(w.y, sv.y, fmaf(w.z, sv.z, fmaf(w.w, sv.w, a[b]))));
    }
  }
  wred<4>(a);
  if (lane == 0) {
    float eb = enc_b[d];
#pragma unroll
    for (int b = 0; b < 4; ++b) h_out[b * D + d] = sigf(a[b] + eb);
  }
}

// ---------------- bit encoder: K frames, MSB first ----------------
__global__ __launch_bounds__(256) void bits_kernel(const float* __restrict__ h,
                                                   float* __restrict__ frames) {
  int idx = blockIdx.x * 256 + threadIdx.x;
  if (idx >= B * D) return;
  float res = h[idx];
#pragma unroll
  for (int k = 0; k < K; ++k) {
    float bit = (res >= 0.5f) ? 1.0f : 0.0f;
    frames[k * B * D + idx] = bit;
    res = (res - 0.5f * bit) * 2.0f;
  }
}

// ---------------- phase 1: gates + membrane update + spikes (per j in DN) ----------------
__global__ __launch_bounds__(256) void phase1_kernel(
    const float* __restrict__ s_in,   // (B,D)
    const float* __restrict__ Vread,  // (B,DN)
    float* __restrict__ Vwrite,       // (B,DN)
    float* __restrict__ sp_out,       // (B,DN)
    const float* __restrict__ WbX, const float* __restrict__ WaX,
    const float* __restrict__ WtX, const float* __restrict__ Win,
    const float* __restrict__ WbV, const float* __restrict__ WaV,
    const float* __restrict__ WtV,
    const float* __restrict__ bb_, const float* __restrict__ ba_,
    const float* __restrict__ bt_) {
  __shared__ float sS[B * D];   // 16KB
  __shared__ float sV[B * DN];  // 32KB
  for (int idx = threadIdx.x; idx < (B * D) / 4; idx += 256)
    ((float4*)sS)[idx] = ((const float4*)s_in)[idx];
  for (int idx = threadIdx.x; idx < (B * DN) / 4; idx += 256)
    ((float4*)sV)[idx] = ((const float4*)Vread)[idx];
  __syncthreads();

  const int lane = threadIdx.x & 63;
  const int j = (blockIdx.x << 2) + (threadIdx.x >> 6);  // 0..2047

  // acc layout: [0..3]=beta, [4..7]=alpha, [8..11]=th, [12..15]=in  (index = type*4 + b)
  float acc[16];
#pragma unroll
  for (int q = 0; q < 16; ++q) acc[q] = 0.f;

  const float4* wbx = (const float4*)(WbX + (size_t)j * D);
  const float4* wax = (const float4*)(WaX + (size_t)j * D);
  const float4* wtx = (const float4*)(WtX + (size_t)j * D);
  const float4* win = (const float4*)(Win + (size_t)j * D);
  for (int c = lane; c < D / 4; c += 64) {
    float4 wb = wbx[c], wa = wax[c], wt = wtx[c], wi = win[c];
#pragma unroll
    for (int b = 0; b < 4; ++b) {
      float4 sv = ((const float4*)(sS + b * D))[c];
      acc[0 + b]  = fmaf(wb.x, sv.x, fmaf(wb.y, sv.y, fmaf(wb.z, sv.z, fmaf(wb.w, sv.w, acc[0 + b]))));
      acc[4 + b]  = fmaf(wa.x, sv.x, fmaf(wa.y, sv.y, fmaf(wa.z, sv.z, fmaf(wa.w, sv.w, acc[4 + b]))));
      acc[8 + b]  = fmaf(wt.x, sv.x, fmaf(wt.y, sv.y, fmaf(wt.z, sv.z, fmaf(wt.w, sv.w, acc[8 + b]))));
      acc[12 + b] = fmaf(wi.x, sv.x, fmaf(wi.y, sv.y, fmaf(wi.z, sv.z, fmaf(wi.w, sv.w, acc[12 + b]))));
    }
  }

  const float4* wbv = (const float4*)(WbV + (size_t)j * DN);
  const float4* wav = (const float4*)(WaV + (size_t)j * DN);
  const float4* wtv = (const float4*)(WtV + (size_t)j * DN);
  for (int c = lane; c < DN / 4; c += 64) {
    float4 wb = wbv[c], wa = wav[c], wt = wtv[c];
#pragma unroll
    for (int b = 0; b < 4; ++b) {
      float4 vv = ((const float4*)(sV + b * DN))[c];
      acc[0 + b] = fmaf(wb.x, vv.x, fmaf(wb.y, vv.y, fmaf(wb.z, vv.z, fmaf(wb.w, vv.w, acc[0 + b]))));
      acc[4 + b] = fmaf(wa.x, vv.x, fmaf(wa.y, vv.y, fmaf(wa.z, vv.z, fmaf(wa.w, vv.w, acc[4 + b]))));
      acc[8 + b] = fmaf(wt.x, vv.x, fmaf(wt.y, vv.y, fmaf(wt.z, vv.z, fmaf(wt.w, vv.w, acc[8 + b]))));
    }
  }

  wred<16>(acc);

  if (lane == 0) {
    float bb = bb_[j], ba = ba_[j], bt = bt_[j];
#pragma unroll
    for (int b = 0; b < 4; ++b) {
      float beta = sigf(acc[0 + b] + bb);
      float alpha = sigf(acc[4 + b] + ba);
      float vth = 0.1f + softplusf(acc[8 + b] + bt);
      float Vold = sV[b * DN + j];
      float Vn = beta * Vold + alpha * acc[12 + b];
      float spike = (Vn - vth >= 0.0f) ? 1.0f : 0.0f;
      Vn = Vn - spike * vth;
      Vwrite[b * DN + j] = Vn;
      sp_out[b * DN + j] = spike;
    }
  }
}

// ---------------- phase 2: output neuron (per d in D) ----------------
__global__ __launch_bounds__(256) void phase2_kernel(
    const float* __restrict__ s_in,   // (B,D)
    const float* __restrict__ sp_in,  // (B,DN)
    float* __restrict__ u,            // (B,D) in/out
    float* __restrict__ so_out,       // (B,D)
    const float* __restrict__ Wgate, const float* __restrict__ Wskip,
    const float* __restrict__ Wout,
    const float* __restrict__ plif_p, const float* __restrict__ vth_p) {
  __shared__ float sS[B * D];   // 16KB
  __shared__ float sP[B * DN];  // 32KB
  for (int idx = threadIdx.x; idx < (B * D) / 4; idx += 256)
    ((float4*)sS)[idx] = ((const float4*)s_in)[idx];
  for (int idx = threadIdx.x; idx < (B * DN) / 4; idx += 256)
    ((float4*)sP)[idx] = ((const float4*)sp_in)[idx];
  __syncthreads();

  const int lane = threadIdx.x & 63;
  const int d = (blockIdx.x << 2) + (threadIdx.x >> 6);  // 0..1023

  // [0..3]=gate, [4..7]=skip, [8..11]=out
  float acc[12];
#pragma unroll
  for (int q = 0; q < 12; ++q) acc[q] = 0.f;

  const float4* wg = (const float4*)(Wgate + (size_t)d * D);
  const float4* wk = (const float4*)(Wskip + (size_t)d * D);
  for (int c = lane; c < D / 4; c += 64) {
    float4 g = wg[c], k = wk[c];
#pragma unroll
    for (int b = 0; b < 4; ++b) {
      float4 sv = ((const float4*)(sS + b * D))[c];
      acc[0 + b] = fmaf(g.x, sv.x, fmaf(g.y, sv.y, fmaf(g.z, sv.z, fmaf(g.w, sv.w, acc[0 + b]))));
      acc[4 + b] = fmaf(k.x, sv.x, fmaf(k.y, sv.y, fmaf(k.z, sv.z, fmaf(k.w, sv.w, acc[4 + b]))));
    }
  }
  const float4* wo = (const float4*)(Wout + (size_t)d * DN);
  for (int c = lane; c < DN / 4; c += 64) {
    float4 o = wo[c];
#pragma unroll
    for (int b = 0; b < 4; ++b) {
      float4 pv = ((const float4*)(sP + b * DN))[c];
      acc[8 + b] = fmaf(o.x, pv.x, fmaf(o.y, pv.y, fmaf(o.z, pv.z, fmaf(o.w, pv.w, acc[8 + b]))));
    }
  }

  wred<12>(acc);

  if (lane == 0) {
    float pl = sigf(plif_p[0]);
    float ovth = vth_p[0];
#pragma unroll
    for (int b = 0; b < 4; ++b) {
      float g = sigf(acc[0 + b]);
      float cur = fmaf(g, acc[8 + b], acc[4 + b]);
      float uo = u[b * D + d];
      float un = uo + (cur - uo) * pl;
      float so = (un - ovth >= 0.0f) ? 1.0f : 0.0f;
      u[b * D + d] = (1.0f - so) * un;
      so_out[b * D + d] = so;
    }
  }
}

// ---------------- decode: weighted bit sum over K frames ----------------
__global__ __launch_bounds__(256) void decode_kernel(const float* __restrict__ outf,
                                                     float* __restrict__ decoded) {
  int idx = blockIdx.x * 256 + threadIdx.x;  // < S*B*D
  int t = idx / (B * D);
  int rem = idx % (B * D);
  float acc = 0.f, w = 0.5f;
#pragma unroll
  for (int k = 0; k < K; ++k) {
    acc = fmaf(outf[(size_t)(t * K + k) * B * D + rem], w, acc);
    w *= 0.5f;
  }
  decoded[idx] = acc;
}

// ---------------- dec GEMM: hh_pre = decoded @ dec_W.T + dec_b  (64 x D) ----------------
__global__ __launch_bounds__(256) void decgemm_kernel(
    const float* __restrict__ decoded,  // (64, D)
    const float* __restrict__ dec_W,    // (D, D)
    const float* __restrict__ dec_b, float* __restrict__ hh_pre) {
  __shared__ float sDec[16 * D];  // 64KB
  const int g = blockIdx.x & 3;   // row group (16 rows)
  for (int idx = threadIdx.x; idx < (16 * D) / 4; idx += 256)
    ((float4*)sDec)[idx] = ((const float4*)(decoded + (size_t)g * 16 * D))[idx];
  __syncthreads();

  const int lane = threadIdx.x & 63;
  const int d = (blockIdx.x >> 2) * 4 + (threadIdx.x >> 6);  // 0..1023
  float acc[16];
#pragma unroll
  for (int q = 0; q < 16; ++q) acc[q] = 0.f;
  const float4* wrow = (const float4*)(dec_W + (size_t)d * D);
  for (int c = lane; c < D / 4; c += 64) {
    float4 w = wrow[c];
#pragma unroll
    for (int r = 0; r < 16; ++r) {
      float4 x = ((const float4*)(sDec + r * D))[c];
      acc[r] = fmaf(w.x, x.x, fmaf(w.y, x.y, fmaf(w.z, x.z, fmaf(w.w, x.w, acc[r]))));
    }
  }
  wred<16>(acc);
  if (lane == 0) {
    float bb = dec_b[d];
#pragma unroll
    for (int r = 0; r < 16; ++r) hh_pre[(size_t)(g * 16 + r) * D + d] = acc[r] + bb;
  }
}

// ---------------- RMSNorm per row ----------------
__global__ __launch_bounds__(256) void rmsnorm_kernel(const float* __restrict__ hh_pre,
                                                      const float* __restrict__ norm_w,
                                                      float* __restrict__ hh) {
  const int r = blockIdx.x;  // 0..63
  const int lane = threadIdx.x & 63, w = threadIdx.x >> 6;
  __shared__ float red[4];
  float ss = 0.f;
  for (int d = threadIdx.x; d < D; d += 256) {
    float v = hh_pre[(size_t)r * D + d];
    ss = fmaf(v, v, ss);
  }
#pragma unroll
  for (int m = 1; m < 64; m <<= 1) ss += __shfl_xor(ss, m, 64);
  if (lane == 0) red[w] = ss;
  __syncthreads();
  float tot = red[0] + red[1] + red[2] + red[3];
  float scale = rsqrtf(tot * (1.0f / D) + 1e-6f);
  for (int d = threadIdx.x; d < D; d += 256)
    hh[(size_t)r * D + d] = norm_w[d] * (hh_pre[(size_t)r * D + d] * scale);
}

// ---------------- LM head: out[b,t,v] += hh[t*B+b,:] . embed[v,:] ----------------
__device__ __forceinline__ unsigned int bf16rn(float f) {
  unsigned int x = __float_as_uint(f);
  return (x + 0x7fffu + ((x >> 16) & 1u)) >> 16;
}

__global__ __launch_bounds__(256) void lmhead_kernel(
    const float* __restrict__ hh,     // (64, D), row = t*B + b
    const float* __restrict__ embed,  // (VOCAB, D)
    float* __restrict__ out) {        // (B, S, VOCAB), pre-zeroed
  __shared__ unsigned int sH[(D / 4) * 64];  // 64KB: bf16x2 of half the D range, [d2][row]
  const int half = blockIdx.x & 1;
  const int vblk = blockIdx.x >> 1;  // 0..255
  const int d0 = half * (D / 2);
  for (int e = threadIdx.x; e < (D / 4) * 64; e += 256) {
    int d2 = e >> 6, r = e & 63;
    float f0 = hh[(size_t)r * D + d0 + 2 * d2];
    float f1 = hh[(size_t)r * D + d0 + 2 * d2 + 1];
    sH[e] = bf16rn(f0) | (bf16rn(f1) << 16);
  }
  __syncthreads();

  const int lane = threadIdx.x & 63;
  const int wave = (vblk << 2) + (threadIdx.x >> 6);  // 0..1023
  for (int v = wave; v < VOCAB; v += 1024) {
    const float4* erow = (const float4*)(embed + (size_t)v * D + d0);
    float acc = 0.f;
#pragma unroll 4
    for (int c = 0; c < (D / 2) / 4; ++c) {  // 128 iters
      float4 e4 = erow[c];  // wave-uniform address (broadcast)
      unsigned int p0 = sH[(c * 2) * 64 + lane];
      unsigned int p1 = sH[(c * 2 + 1) * 64 + lane];
      float h0 = __uint_as_float(p0 << 16);
      float h1 = __uint_as_float(p0 & 0xffff0000u);
      float h2 = __uint_as_float(p1 << 16);
      float h3 = __uint_as_float(p1 & 0xffff0000u);
      acc = fmaf(e4.x, h0, fmaf(e4.y, h1, fmaf(e4.z, h2, fmaf(e4.w, h3, acc))));
    }
    int tt = lane >> 2, b = lane & 3;  // row = lane = t*B + b
    atomicAdd(&out[((size_t)b * S + tt) * VOCAB + v], acc);
  }
}

extern "C" void kernel_launch(void* const* d_in, const int* in_sizes, int n_in,
                              void* d_out, int out_size, void* d_ws, size_t ws_size,
                              hipStream_t stream) {
  const int* token_ids = (const int*)d_in[0];
  const float* embed   = (const float*)d_in[1];
  const float* norm_w  = (const float*)d_in[2];
  const float* enc_W   = (const float*)d_in[3];
  const float* enc_b   = (const float*)d_in[4];
  const float* dec_W   = (const float*)d_in[5];
  const float* dec_b   = (const float*)d_in[6];
  const float* Win     = (const float*)d_in[7];
  const float* WbX     = (const float*)d_in[8];
  const float* WaX     = (const float*)d_in[9];
  const float* WtX     = (const float*)d_in[10];
  const float* WbV     = (const float*)d_in[11];
  const float* WaV     = (const float*)d_in[12];
  const float* WtV     = (const float*)d_in[13];
  const float* b_beta  = (const float*)d_in[14];
  const float* b_alpha = (const float*)d_in[15];
  const float* b_th    = (const float*)d_in[16];
  const float* Wgate   = (const float*)d_in[17];
  const float* Wskip   = (const float*)d_in[18];
  const float* Wout    = (const float*)d_in[19];
  const float* plif_w  = (const float*)d_in[20];
  const float* out_vth = (const float*)d_in[21];

  float* ws = (float*)d_ws;
  float* frames  = ws;                        // K*B*D      = 32768
  float* Vbuf    = frames + K * B * D;        // 2*NB*B*DN  = 65536
  float* u       = Vbuf + 2 * NB * B * DN;    // NB*B*D     = 16384
  float* sp      = u + NB * B * D;            // B*DN       = 8192
  float* so      = sp + B * DN;               // NB*B*D     = 16384
  float* outf    = so + NB * B * D;           // S*K*B*D    = 524288
  float* h       = outf + S * K * B * D;      // B*D        = 4096
  float* decoded = h + B * D;                 // S*B*D      = 65536
  float* hh_pre  = decoded + S * B * D;       // S*B*D      = 65536
  float* hh      = hh_pre + S * B * D;        // S*B*D      = 65536

  hipMemsetAsync(Vbuf, 0, (size_t)NB * B * DN * sizeof(float), stream);
  hipMemsetAsync(u, 0, (size_t)NB * B * D * sizeof(float), stream);
  hipMemsetAsync(d_out, 0, (size_t)out_size * sizeof(float), stream);

  for (int t = 0; t < S; ++t) {
    enc_kernel<<<256, 256, 0, stream>>>(token_ids, t, embed, enc_W, enc_b, h);
    bits_kernel<<<16, 256, 0, stream>>>(h, frames);
    for (int k = 0; k < K; ++k) {
      int p = (t * K + k) & 1;
      const float* s_cur = frames + (size_t)k * B * D;
      for (int i = 0; i < NB; ++i) {
        const float* Vr = Vbuf + (size_t)p * NB * B * DN + (size_t)i * B * DN;
        float* Vw = Vbuf + (size_t)(1 - p) * NB * B * DN + (size_t)i * B * DN;
        phase1_kernel<<<512, 256, 0, stream>>>(
            s_cur, Vr, Vw, sp,
            WbX + (size_t)i * DN * D, WaX + (size_t)i * DN * D,
            WtX + (size_t)i * DN * D, Win + (size_t)i * DN * D,
            WbV + (size_t)i * DN * DN, WaV + (size_t)i * DN * DN,
            WtV + (size_t)i * DN * DN,
            b_beta + i * DN, b_alpha + i * DN, b_th + i * DN);
        float* dest = (i < NB - 1) ? (so + (size_t)i * B * D)
                                   : (outf + (size_t)(t * K + k) * B * D);
        phase2_kernel<<<256, 256, 0, stream>>>(
            s_cur, sp, u + (size_t)i * B * D, dest,
            Wgate + (size_t)i * D * D, Wskip + (size_t)i * D * D,
            Wout + (size_t)i * D * DN, plif_w + i, out_vth + i);
        s_cur = dest;
      }
    }
  }
  decode_kernel<<<(S * B * D) / 256, 256, 0, stream>>>(outf, decoded);
  decgemm_kernel<<<1024, 256, 0, stream>>>(decoded, dec_W, dec_b, hh_pre);
  rmsnorm_kernel<<<S * B, 256, 0, stream>>>(hh_pre, norm_w, hh);
  lmhead_kernel<<<512, 256, 0, stream>>>(hh, embed, (float*)d_out);
}